// Round 8
// baseline (623.452 us; speedup 1.0000x reference)
//
#include <hip/hip_runtime.h>
#include <hip/hip_bf16.h>
#include <math.h>

// Problem constants
#define BB 2
#define TT 512
#define DM 1024
#define DI 2048
#define DCONV 4
#define NH 32
#define NS 32
#define DH 64
#define PROJW 4160   // 2*DI + NH*2
#define BT (BB*TT)   // 1024

typedef unsigned short u16;
typedef short bf16x8v __attribute__((ext_vector_type(8)));
typedef float f32x4 __attribute__((ext_vector_type(4)));
typedef u16 u16x4 __attribute__((ext_vector_type(4)));

__device__ __forceinline__ float sigmoidf_(float x) { return 1.0f / (1.0f + expf(-x)); }
__device__ __forceinline__ float siluf_(float x) { return x * sigmoidf_(x); }

// RNE split: x ~= h + s (both bf16), returned by value
struct HS { u16 h, s; };
__device__ __forceinline__ HS split1(float x) {
    HS r;
    unsigned u = __float_as_uint(x);
    unsigned rr = u + 0x7fffu + ((u >> 16) & 1u);
    r.h = (u16)(rr >> 16);
    float hf = __uint_as_float(((unsigned)r.h) << 16);
    float res = x - hf;
    unsigned u2 = __float_as_uint(res);
    unsigned r2 = u2 + 0x7fffu + ((u2 >> 16) & 1u);
    r.s = (u16)(r2 >> 16);
    return r;
}

__device__ __forceinline__ void async_copy16(const void* g, void* l) {
    __builtin_amdgcn_global_load_lds(
        (__attribute__((address_space(1))) void*)const_cast<void*>(g),
        (__attribute__((address_space(3))) void*)l,
        16, 0, 0);
}

__device__ __forceinline__ void async_copy4(const void* g, void* l) {
    __builtin_amdgcn_global_load_lds(
        (__attribute__((address_space(1))) void*)const_cast<void*>(g),
        (__attribute__((address_space(3))) void*)l,
        4, 0, 0);
}

// elementwise fp32 -> (hi, lo) bf16 arrays, 4 elems/thread
__global__ __launch_bounds__(256) void split_kernel(const float* __restrict__ in,
                                                    u16* __restrict__ hi,
                                                    u16* __restrict__ lo,
                                                    int n4) {
    int i = blockIdx.x * 256 + threadIdx.x;
    if (i >= n4) return;
    float4 v = ((const float4*)in)[i];
    HS a = split1(v.x), b = split1(v.y), c = split1(v.z), d = split1(v.w);
    u16x4 h, s;
    h.x = a.h; h.y = b.h; h.z = c.h; h.w = d.h;
    s.x = a.s; s.y = b.s; s.z = c.s; s.w = d.s;
    ((u16x4*)hi)[i] = h;
    ((u16x4*)lo)[i] = s;
}

// ---------------------------------------------------------------------------
// bf16x3 MFMA NT-GEMM: C[m,n] = sum_k A[m,k]*B[n,k], A=Ah+Al, B=Bh+Bl.
// 256 threads = 4 waves (2x2). Per wave: MF x NF 16x16 frags.
// LDS tiles [rows][32] bf16, staged via global_load_lds (16B/lane).
// ---------------------------------------------------------------------------
template<int BM, int BN, bool GUARD>
__global__ __launch_bounds__(256) void gemm_bf16x3(const u16* __restrict__ Ah,
                                                   const u16* __restrict__ Al,
                                                   const u16* __restrict__ Bh,
                                                   const u16* __restrict__ Bl,
                                                   float* __restrict__ C,
                                                   int M, int N, int K) {
    constexpr int MF = BM / 32;
    constexpr int NF = BN / 32;
    constexpr int ASEG = BM / 16, BSEG = BN / 16;
    constexpr int NSEG = 2 * ASEG + 2 * BSEG;
    constexpr int SEGW = NSEG / 4;

    __shared__ u16 lds[(2 * BM + 2 * BN) * 32];
    u16* Ah_s = lds;
    u16* Al_s = lds + BM * 32;
    u16* Bh_s = lds + 2 * BM * 32;
    u16* Bl_s = lds + (2 * BM + BN) * 32;

    const int tid = threadIdx.x;
    const int l = tid & 63;
    const int w = tid >> 6;
    const int wm = w >> 1, wn = w & 1;

    const int m0 = blockIdx.y * BM;
    const int n0 = blockIdx.x * BN;

    // staging segment setup: seg -> (global base, lds base)
    const u16* segg[SEGW];
    u16* segl[SEGW];
#pragma unroll
    for (int si = 0; si < SEGW; ++si) {
        int seg = w + si * 4;
        const u16* gmat;
        u16* lmat;
        int r0, rbase;
        if (seg < ASEG)                { gmat = Ah; lmat = Ah_s; r0 = seg * 16;                  rbase = m0; }
        else if (seg < 2 * ASEG)       { gmat = Al; lmat = Al_s; r0 = (seg - ASEG) * 16;         rbase = m0; }
        else if (seg < 2 * ASEG + BSEG){ gmat = Bh; lmat = Bh_s; r0 = (seg - 2 * ASEG) * 16;     rbase = n0; }
        else                           { gmat = Bl; lmat = Bl_s; r0 = (seg - 2 * ASEG - BSEG) * 16; rbase = n0; }
        segg[si] = gmat + (size_t)(rbase + r0 + (l >> 2)) * K + (l & 3) * 8;
        segl[si] = lmat + r0 * 32;
    }

    f32x4 acc[MF][NF];
#pragma unroll
    for (int i = 0; i < MF; ++i)
#pragma unroll
        for (int j = 0; j < NF; ++j) {
            f32x4 z = {0.0f, 0.0f, 0.0f, 0.0f};
            acc[i][j] = z;
        }

    const int lrow = l & 15;
    const int lko = (l >> 4) * 8;

    for (int k0 = 0; k0 < K; k0 += 32) {
#pragma unroll
        for (int si = 0; si < SEGW; ++si)
            async_copy16(segg[si] + k0, segl[si]);
        __syncthreads();

        bf16x8v af[MF][2], bfv[NF][2];
#pragma unroll
        for (int i = 0; i < MF; ++i) {
            int r = wm * (MF * 16) + i * 16 + lrow;
            af[i][0] = *(const bf16x8v*)&Ah_s[r * 32 + lko];
            af[i][1] = *(const bf16x8v*)&Al_s[r * 32 + lko];
        }
#pragma unroll
        for (int j = 0; j < NF; ++j) {
            int r = wn * (NF * 16) + j * 16 + lrow;
            bfv[j][0] = *(const bf16x8v*)&Bh_s[r * 32 + lko];
            bfv[j][1] = *(const bf16x8v*)&Bl_s[r * 32 + lko];
        }
#pragma unroll
        for (int i = 0; i < MF; ++i)
#pragma unroll
            for (int j = 0; j < NF; ++j) {
                acc[i][j] = __builtin_amdgcn_mfma_f32_16x16x32_bf16(af[i][0], bfv[j][0], acc[i][j], 0, 0, 0);
                acc[i][j] = __builtin_amdgcn_mfma_f32_16x16x32_bf16(af[i][0], bfv[j][1], acc[i][j], 0, 0, 0);
                acc[i][j] = __builtin_amdgcn_mfma_f32_16x16x32_bf16(af[i][1], bfv[j][0], acc[i][j], 0, 0, 0);
            }
        __syncthreads();
    }

    // store: D row=(l>>4)*4+reg, col=l&15  [m89 layout]
#pragma unroll
    for (int i = 0; i < MF; ++i) {
        int mrow = m0 + wm * (MF * 16) + i * 16 + (l >> 4) * 4;
#pragma unroll
        for (int j = 0; j < NF; ++j) {
            int ncol = n0 + wn * (NF * 16) + j * 16 + lrow;
            if (!GUARD || ncol < N) {
#pragma unroll
                for (int r = 0; r < 4; ++r)
                    C[(size_t)(mrow + r) * N + ncol] = acc[i][j][r];
            }
        }
    }
}

// depthwise causal conv (K=4) + SiLU, 4 channels/thread; also writes bf16 split
__global__ __launch_bounds__(256) void conv_silu_kernel(const float* __restrict__ proj,
                                                        const float* __restrict__ dw_w,
                                                        const float* __restrict__ dw_b,
                                                        float* __restrict__ value,
                                                        u16* __restrict__ vh,
                                                        u16* __restrict__ vl) {
    int i = blockIdx.x * 256 + threadIdx.x;      // < BT*DI/4
    int dq = i & (DI / 4 - 1);
    int bt = i >> 9;
    int t = bt & (TT - 1);
    int di = dq * 4;
    const float* vr = proj + (size_t)bt * PROJW + DI + di;
    float4 zz = {0, 0, 0, 0};
    float4 x0 = (t >= 3) ? *(const float4*)(vr - 3 * PROJW) : zz;
    float4 x1 = (t >= 2) ? *(const float4*)(vr - 2 * PROJW) : zz;
    float4 x2 = (t >= 1) ? *(const float4*)(vr - 1 * PROJW) : zz;
    float4 x3 = *(const float4*)vr;
    float4 w0 = *(const float4*)&dw_w[(di + 0) * 4];
    float4 w1 = *(const float4*)&dw_w[(di + 1) * 4];
    float4 w2 = *(const float4*)&dw_w[(di + 2) * 4];
    float4 w3 = *(const float4*)&dw_w[(di + 3) * 4];
    float4 bb = *(const float4*)&dw_b[di];
    float4 v;
    v.x = siluf_(bb.x + x0.x * w0.x + x1.x * w0.y + x2.x * w0.z + x3.x * w0.w);
    v.y = siluf_(bb.y + x0.y * w1.x + x1.y * w1.y + x2.y * w1.z + x3.y * w1.w);
    v.z = siluf_(bb.z + x0.z * w2.x + x1.z * w2.y + x2.z * w2.z + x3.z * w2.w);
    v.w = siluf_(bb.w + x0.w * w3.x + x1.w * w3.y + x2.w * w3.z + x3.w * w3.w);
    ((float4*)value)[i] = v;
    HS a = split1(v.x), b = split1(v.y), c = split1(v.z), d = split1(v.w);
    u16x4 h, s;
    h.x = a.h; h.y = b.h; h.z = c.h; h.w = d.h;
    s.x = a.s; s.y = b.s; s.z = c.s; s.w = d.s;
    ((u16x4*)vh)[i] = h;
    ((u16x4*)vl)[i] = s;
}

// per (bt,h,n): dt (softplus+clip), S = 1/(1 + dt*kd + dt^2*A)
__global__ __launch_bounds__(256) void dtkd_S_kernel(const float* __restrict__ proj,
                                                     const float* __restrict__ dt_bias,
                                                     const float* __restrict__ A_log,
                                                     float* __restrict__ dt_a,
                                                     float* __restrict__ S_a) {
    int idx = blockIdx.x * 256 + threadIdx.x;     // < BT*NH*NS
    int n = idx & (NS - 1);
    int h = (idx >> 5) & (NH - 1);
    int bt = idx >> 10;
    const float* prow = proj + (size_t)bt * PROJW + 2 * DI;
    float p0 = prow[2 * h], p1 = prow[2 * h + 1];
    float xdt = p0 + dt_bias[h];
    float sp = fmaxf(xdt, 0.0f) + log1pf(expf(-fabsf(xdt)));
    float dt = fminf(fmaxf(sp, 1e-4f), 0.1f);
    float kd = 0.5f * sigmoidf_(p1);
    float A = expf(A_log[h * NS + n]);
    float S = 1.0f / (1.0f + dt * kd + dt * dt * A);
    S_a[idx] = S;
    if (n == 0) dt_a[bt * NH + h] = dt;
}

// L2-normalize bc over groups of 32
__global__ __launch_bounds__(256) void normalize_kernel(float* __restrict__ bc) {
    int idx = blockIdx.x * 256 + threadIdx.x;     // < BT*4096
    float v = bc[idx];
    float ss = v * v;
    ss += __shfl_xor(ss, 1);
    ss += __shfl_xor(ss, 2);
    ss += __shfl_xor(ss, 4);
    ss += __shfl_xor(ss, 8);
    ss += __shfl_xor(ss, 16);
    bc[idx] = v / (sqrtf(ss) + 1e-8f);
}

// ---------------------------------------------------------------------------
// sequential scan, deep-pipelined: per-wave-private LDS circular buffer,
// depth 8 slots, 6 steps in flight, 3 global_load_lds gathers/step/wave,
// constant vmcnt(18) wait. No barriers (waves fully independent).
// One block per (b,h); wave w owns d in [16w,16w+16); lane group ng owns
// n in [8ng, 8ng+8). Slot layout (192 floats): [0..128) bc row
// (bz|bx|cz|cx), [128..160) S, [160..176) u (this wave's d-range),
// [176] dt (lanes 48..63 all write dt — harmless dup).
// ---------------------------------------------------------------------------
#define SCAN_D 6
#define SCAN_SLOTS 8

__global__ __launch_bounds__(256, 1) void scan_kernel(const float* __restrict__ value,
                                                      const float* __restrict__ bc,
                                                      const float* __restrict__ dt_a,
                                                      const float* __restrict__ S_a,
                                                      const float* __restrict__ A_log,
                                                      float* __restrict__ yout) {
    __shared__ float slots[4][SCAN_SLOTS][192];
    const int bh = blockIdx.x;
    const int b = bh >> 5, h = bh & (NH - 1);
    const int tid = threadIdx.x;
    const int w = tid >> 6, l = tid & 63;
    const int dloc = l & 15;
    const int d = w * 16 + dloc;
    const int ng = l >> 4;
    const int n0 = ng * 8;

    float a[8];
#pragma unroll
    for (int j = 0; j < 8; j++) a[j] = expf(A_log[h * NS + n0 + j]);

    float z[8], s[8];
#pragma unroll
    for (int j = 0; j < 8; j++) { z[j] = 0.0f; s[j] = 0.0f; }

    // per-lane gather pointers (advance per step)
    const float* gA = bc + (size_t)b * TT * 4096 + h * 128 + l;        // bz|bx half
    const float* gB = gA + 64;                                         // cz|cx half
    const float* gC;
    size_t strC;
    if (l < 32)      { gC = S_a   + (size_t)b * TT * (NH * NS) + h * NS + l;          strC = NH * NS; }
    else if (l < 48) { gC = value + (size_t)b * TT * DI + h * DH + w * 16 + (l - 32); strC = DI; }
    else             { gC = dt_a  + (size_t)b * TT * NH + h;                          strC = NH; }

    float* yp = yout + (size_t)b * TT * DI + h * DH + d;

    // prologue: issue steps 0..SCAN_D-1
    for (int k = 0; k < SCAN_D; ++k) {
        float* dst = &slots[w][k][0];
        async_copy4(gA, dst);
        async_copy4(gB, dst + 64);
        async_copy4(gC, dst + 128);
        gA += 4096; gB += 4096; gC += strC;
    }

    for (int t = 0; t < TT; ++t) {
        // issue step t+SCAN_D (clamped source at TT-1, rotating slot)
        {
            float* dst = &slots[w][(t + SCAN_D) & (SCAN_SLOTS - 1)][0];
            async_copy4(gA, dst);
            async_copy4(gB, dst + 64);
            async_copy4(gC, dst + 128);
            if (t + SCAN_D < TT - 1) { gA += 4096; gB += 4096; gC += strC; }
        }

        // wait until step t's 3 loads (oldest) are done: 3*SCAN_D remain
        asm volatile("s_waitcnt vmcnt(18)" ::: "memory");
        __builtin_amdgcn_sched_barrier(0);

        const float* csl = &slots[w][t & (SCAN_SLOTS - 1)][0];
        float bz[8], bx[8], cz[8], cx[8], Sv[8];
        *(float4*)&bz[0] = *(const float4*)&csl[n0];
        *(float4*)&bz[4] = *(const float4*)&csl[n0 + 4];
        *(float4*)&bx[0] = *(const float4*)&csl[32 + n0];
        *(float4*)&bx[4] = *(const float4*)&csl[32 + n0 + 4];
        *(float4*)&cz[0] = *(const float4*)&csl[64 + n0];
        *(float4*)&cz[4] = *(const float4*)&csl[64 + n0 + 4];
        *(float4*)&cx[0] = *(const float4*)&csl[96 + n0];
        *(float4*)&cx[4] = *(const float4*)&csl[96 + n0 + 4];
        *(float4*)&Sv[0] = *(const float4*)&csl[128 + n0];
        *(float4*)&Sv[4] = *(const float4*)&csl[128 + n0 + 4];
        float u_d = csl[160 + dloc];
        float dt = csl[176];

        float dtu = dt * u_d;
        float y0 = 0.0f, y1 = 0.0f;
#pragma unroll
        for (int j = 0; j < 8; j++) {
            float dtA = dt * a[j];
            float t1v = fmaf(-dtA, s[j], z[j]);
            float t2v = fmaf(dtu, bz[j], t1v);
            float zn = Sv[j] * t2v;
            z[j] = zn;
            float sn = fmaf(dt, zn, fmaf(dtu, bx[j], s[j]));
            s[j] = sn;
            if (j & 1) { y1 = fmaf(cz[j], zn, y1); y1 = fmaf(cx[j], sn, y1); }
            else       { y0 = fmaf(cz[j], zn, y0); y0 = fmaf(cx[j], sn, y0); }
        }
        float y = y0 + y1;
        y += __shfl_xor(y, 16);
        y += __shfl_xor(y, 32);
        if (ng == 0) yp[(size_t)t * DI] = y;
    }
}

// y = (y + skip*value) * silu(gate); writes bf16 split only (consumed by GEMM3)
__global__ __launch_bounds__(256) void fuse_kernel(const float* __restrict__ proj,
                                                   const float* __restrict__ value,
                                                   const float* __restrict__ skip,
                                                   const float* __restrict__ ysc,
                                                   u16* __restrict__ yh,
                                                   u16* __restrict__ yl) {
    int i = blockIdx.x * 256 + threadIdx.x;      // < BT*DI/4
    int dq = i & (DI / 4 - 1);
    int bt = i >> 9;
    int di = dq * 4;
    float4 g = *(const float4*)&proj[(size_t)bt * PROJW + di];
    float4 yv = ((const float4*)ysc)[i];
    float4 v = ((const float4*)value)[i];
    float4 sk = *(const float4*)&skip[di];
    float4 r;
    r.x = fmaf(sk.x, v.x, yv.x) * siluf_(g.x);
    r.y = fmaf(sk.y, v.y, yv.y) * siluf_(g.y);
    r.z = fmaf(sk.z, v.z, yv.z) * siluf_(g.z);
    r.w = fmaf(sk.w, v.w, yv.w) * siluf_(g.w);
    HS a = split1(r.x), b = split1(r.y), c = split1(r.z), d = split1(r.w);
    u16x4 h, s;
    h.x = a.h; h.y = b.h; h.z = c.h; h.w = d.h;
    s.x = a.s; s.y = b.s; s.z = c.s; s.w = d.s;
    ((u16x4*)yh)[i] = h;
    ((u16x4*)yl)[i] = s;
}

extern "C" void kernel_launch(void* const* d_in, const int* in_sizes, int n_in,
                              void* d_out, int out_size, void* d_ws, size_t ws_size,
                              hipStream_t stream) {
    const float* x       = (const float*)d_in[0];
    const float* W_in    = (const float*)d_in[1];
    const float* dw_w    = (const float*)d_in[2];
    const float* dw_b    = (const float*)d_in[3];
    const float* W_bc    = (const float*)d_in[4];
    const float* W_out   = (const float*)d_in[5];
    const float* skip    = (const float*)d_in[6];
    const float* A_log   = (const float*)d_in[7];
    const float* dt_bias = (const float*)d_in[8];
    float* out = (float*)d_out;

    float* ws    = (float*)d_ws;
    float* proj  = ws;                                // 4,259,840 f
    float* value = proj  + (size_t)BT * PROJW;        // 2,097,152
    float* dt_a  = value + (size_t)BT * DI;           // 32,768
    float* S_a   = dt_a  + (size_t)BT * NH;           // 1,048,576
    float* bcw   = S_a   + (size_t)BT * NH * NS;      // 4,194,304
    float* ysc   = bcw   + (size_t)BT * 4096;         // 2,097,152
    u16* Aslot_h = (u16*)(ysc + (size_t)BT * DI);     // 2,097,152 u16
    u16* Aslot_l = Aslot_h + 2097152;                 // 2,097,152
    u16* Bslot_h = Aslot_l + 2097152;                 // 8,388,608
    u16* Bslot_l = Bslot_h + 8388608;                 // 8,388,608

    dim3 blk(256);

    // splits for GEMM1: A = x (1,048,576), B = W_in (4,259,840)
    split_kernel<<<dim3(1048576 / 4 / 256), blk, 0, stream>>>(x, Aslot_h, Aslot_l, 1048576 / 4);
    split_kernel<<<dim3(4259840 / 4 / 256), blk, 0, stream>>>(W_in, Bslot_h, Bslot_l, 4259840 / 4);

    // 1) proj = x @ W_in^T : M=1024, N=4160, K=1024 (N edge guarded)
    gemm_bf16x3<64, 128, true><<<dim3(33, 16), blk, 0, stream>>>(
        Aslot_h, Aslot_l, Bslot_h, Bslot_l, proj, BT, PROJW, DM);

    // 2) conv + silu -> value (fp32 + bf16 split into A slot)
    conv_silu_kernel<<<dim3(BT * DI / 4 / 256), blk, 0, stream>>>(
        proj, dw_w, dw_b, value, Aslot_h, Aslot_l);

    // 3) dt + S precompute
    dtkd_S_kernel<<<dim3(BT * NH * NS / 256), blk, 0, stream>>>(proj, dt_bias, A_log, dt_a, S_a);

    // split B = W_bc (8,388,608)
    split_kernel<<<dim3(8388608 / 4 / 256), blk, 0, stream>>>(W_bc, Bslot_h, Bslot_l, 8388608 / 4);

    // 4) bc = value @ W_bc^T : M=1024, N=4096, K=2048
    gemm_bf16x3<64, 128, false><<<dim3(32, 16), blk, 0, stream>>>(
        Aslot_h, Aslot_l, Bslot_h, Bslot_l, bcw, BT, 4096, DI);

    // 5) normalize
    normalize_kernel<<<dim3(BT * 4096 / 256), blk, 0, stream>>>(bcw);

    // 6) scan (deep-pipelined LDS circular buffer)
    scan_kernel<<<dim3(BB * NH), blk, 0, stream>>>(value, bcw, dt_a, S_a, A_log, ysc);

    // 7) fuse skip/gate -> bf16 split into A slot
    fuse_kernel<<<dim3(BT * DI / 4 / 256), blk, 0, stream>>>(
        proj, value, skip, ysc, Aslot_h, Aslot_l);

    // split B = W_out (2,097,152)
    split_kernel<<<dim3(2097152 / 4 / 256), blk, 0, stream>>>(W_out, Bslot_h, Bslot_l, 2097152 / 4);

    // 8) out = y @ W_out^T : M=1024, N=1024, K=2048
    gemm_bf16x3<64, 64, false><<<dim3(16, 16), blk, 0, stream>>>(
        Aslot_h, Aslot_l, Bslot_h, Bslot_l, out, BT, DM, DI);
}

// Round 9
// 457.141 us; speedup vs baseline: 1.3638x; 1.3638x over previous
//
#include <hip/hip_runtime.h>
#include <hip/hip_bf16.h>
#include <math.h>

// Problem constants
#define BB 2
#define TT 512
#define DM 1024
#define DI 2048
#define DCONV 4
#define NH 32
#define NS 32
#define DH 64
#define PROJW 4160   // 2*DI + NH*2
#define BT (BB*TT)   // 1024

typedef unsigned short u16;
typedef short bf16x8v __attribute__((ext_vector_type(8)));
typedef float f32x4 __attribute__((ext_vector_type(4)));
typedef u16 u16x4 __attribute__((ext_vector_type(4)));

__device__ __forceinline__ float sigmoidf_(float x) { return 1.0f / (1.0f + expf(-x)); }
__device__ __forceinline__ float siluf_(float x) { return x * sigmoidf_(x); }

// RNE split: x ~= h + s (both bf16), returned by value
struct HS { u16 h, s; };
__device__ __forceinline__ HS split1(float x) {
    HS r;
    unsigned u = __float_as_uint(x);
    unsigned rr = u + 0x7fffu + ((u >> 16) & 1u);
    r.h = (u16)(rr >> 16);
    float hf = __uint_as_float(((unsigned)r.h) << 16);
    float res = x - hf;
    unsigned u2 = __float_as_uint(res);
    unsigned r2 = u2 + 0x7fffu + ((u2 >> 16) & 1u);
    r.s = (u16)(r2 >> 16);
    return r;
}

__device__ __forceinline__ void async_copy16(const void* g, void* l) {
    __builtin_amdgcn_global_load_lds(
        (__attribute__((address_space(1))) void*)const_cast<void*>(g),
        (__attribute__((address_space(3))) void*)l,
        16, 0, 0);
}

__device__ __forceinline__ void async_copy4(const void* g, void* l) {
    __builtin_amdgcn_global_load_lds(
        (__attribute__((address_space(1))) void*)const_cast<void*>(g),
        (__attribute__((address_space(3))) void*)l,
        4, 0, 0);
}

// elementwise fp32 -> (hi, lo) bf16 arrays, 4 elems/thread
__global__ __launch_bounds__(256) void split_kernel(const float* __restrict__ in,
                                                    u16* __restrict__ hi,
                                                    u16* __restrict__ lo,
                                                    int n4) {
    int i = blockIdx.x * 256 + threadIdx.x;
    if (i >= n4) return;
    float4 v = ((const float4*)in)[i];
    HS a = split1(v.x), b = split1(v.y), c = split1(v.z), d = split1(v.w);
    u16x4 h, s;
    h.x = a.h; h.y = b.h; h.z = c.h; h.w = d.h;
    s.x = a.s; s.y = b.s; s.z = c.s; s.w = d.s;
    ((u16x4*)hi)[i] = h;
    ((u16x4*)lo)[i] = s;
}

// ---------------------------------------------------------------------------
// bf16x3 MFMA NT-GEMM: C[m,n] = sum_k A[m,k]*B[n,k], A=Ah+Al, B=Bh+Bl.
// ---------------------------------------------------------------------------
template<int BM, int BN, bool GUARD>
__global__ __launch_bounds__(256) void gemm_bf16x3(const u16* __restrict__ Ah,
                                                   const u16* __restrict__ Al,
                                                   const u16* __restrict__ Bh,
                                                   const u16* __restrict__ Bl,
                                                   float* __restrict__ C,
                                                   int M, int N, int K) {
    constexpr int MF = BM / 32;
    constexpr int NF = BN / 32;
    constexpr int ASEG = BM / 16, BSEG = BN / 16;
    constexpr int NSEG = 2 * ASEG + 2 * BSEG;
    constexpr int SEGW = NSEG / 4;

    __shared__ u16 lds[(2 * BM + 2 * BN) * 32];
    u16* Ah_s = lds;
    u16* Al_s = lds + BM * 32;
    u16* Bh_s = lds + 2 * BM * 32;
    u16* Bl_s = lds + (2 * BM + BN) * 32;

    const int tid = threadIdx.x;
    const int l = tid & 63;
    const int w = tid >> 6;
    const int wm = w >> 1, wn = w & 1;

    const int m0 = blockIdx.y * BM;
    const int n0 = blockIdx.x * BN;

    const u16* segg[SEGW];
    u16* segl[SEGW];
#pragma unroll
    for (int si = 0; si < SEGW; ++si) {
        int seg = w + si * 4;
        const u16* gmat;
        u16* lmat;
        int r0, rbase;
        if (seg < ASEG)                { gmat = Ah; lmat = Ah_s; r0 = seg * 16;                  rbase = m0; }
        else if (seg < 2 * ASEG)       { gmat = Al; lmat = Al_s; r0 = (seg - ASEG) * 16;         rbase = m0; }
        else if (seg < 2 * ASEG + BSEG){ gmat = Bh; lmat = Bh_s; r0 = (seg - 2 * ASEG) * 16;     rbase = n0; }
        else                           { gmat = Bl; lmat = Bl_s; r0 = (seg - 2 * ASEG - BSEG) * 16; rbase = n0; }
        segg[si] = gmat + (size_t)(rbase + r0 + (l >> 2)) * K + (l & 3) * 8;
        segl[si] = lmat + r0 * 32;
    }

    f32x4 acc[MF][NF];
#pragma unroll
    for (int i = 0; i < MF; ++i)
#pragma unroll
        for (int j = 0; j < NF; ++j) {
            f32x4 z = {0.0f, 0.0f, 0.0f, 0.0f};
            acc[i][j] = z;
        }

    const int lrow = l & 15;
    const int lko = (l >> 4) * 8;

    for (int k0 = 0; k0 < K; k0 += 32) {
#pragma unroll
        for (int si = 0; si < SEGW; ++si)
            async_copy16(segg[si] + k0, segl[si]);
        __syncthreads();

        bf16x8v af[MF][2], bfv[NF][2];
#pragma unroll
        for (int i = 0; i < MF; ++i) {
            int r = wm * (MF * 16) + i * 16 + lrow;
            af[i][0] = *(const bf16x8v*)&Ah_s[r * 32 + lko];
            af[i][1] = *(const bf16x8v*)&Al_s[r * 32 + lko];
        }
#pragma unroll
        for (int j = 0; j < NF; ++j) {
            int r = wn * (NF * 16) + j * 16 + lrow;
            bfv[j][0] = *(const bf16x8v*)&Bh_s[r * 32 + lko];
            bfv[j][1] = *(const bf16x8v*)&Bl_s[r * 32 + lko];
        }
#pragma unroll
        for (int i = 0; i < MF; ++i)
#pragma unroll
            for (int j = 0; j < NF; ++j) {
                acc[i][j] = __builtin_amdgcn_mfma_f32_16x16x32_bf16(af[i][0], bfv[j][0], acc[i][j], 0, 0, 0);
                acc[i][j] = __builtin_amdgcn_mfma_f32_16x16x32_bf16(af[i][0], bfv[j][1], acc[i][j], 0, 0, 0);
                acc[i][j] = __builtin_amdgcn_mfma_f32_16x16x32_bf16(af[i][1], bfv[j][0], acc[i][j], 0, 0, 0);
            }
        __syncthreads();
    }

#pragma unroll
    for (int i = 0; i < MF; ++i) {
        int mrow = m0 + wm * (MF * 16) + i * 16 + (l >> 4) * 4;
#pragma unroll
        for (int j = 0; j < NF; ++j) {
            int ncol = n0 + wn * (NF * 16) + j * 16 + lrow;
            if (!GUARD || ncol < N) {
#pragma unroll
                for (int r = 0; r < 4; ++r)
                    C[(size_t)(mrow + r) * N + ncol] = acc[i][j][r];
            }
        }
    }
}

// depthwise causal conv (K=4) + SiLU, 4 channels/thread; also writes bf16 split
__global__ __launch_bounds__(256) void conv_silu_kernel(const float* __restrict__ proj,
                                                        const float* __restrict__ dw_w,
                                                        const float* __restrict__ dw_b,
                                                        float* __restrict__ value,
                                                        u16* __restrict__ vh,
                                                        u16* __restrict__ vl) {
    int i = blockIdx.x * 256 + threadIdx.x;      // < BT*DI/4
    int dq = i & (DI / 4 - 1);
    int bt = i >> 9;
    int t = bt & (TT - 1);
    int di = dq * 4;
    const float* vr = proj + (size_t)bt * PROJW + DI + di;
    float4 zz = {0, 0, 0, 0};
    float4 x0 = (t >= 3) ? *(const float4*)(vr - 3 * PROJW) : zz;
    float4 x1 = (t >= 2) ? *(const float4*)(vr - 2 * PROJW) : zz;
    float4 x2 = (t >= 1) ? *(const float4*)(vr - 1 * PROJW) : zz;
    float4 x3 = *(const float4*)vr;
    float4 w0 = *(const float4*)&dw_w[(di + 0) * 4];
    float4 w1 = *(const float4*)&dw_w[(di + 1) * 4];
    float4 w2 = *(const float4*)&dw_w[(di + 2) * 4];
    float4 w3 = *(const float4*)&dw_w[(di + 3) * 4];
    float4 bb = *(const float4*)&dw_b[di];
    float4 v;
    v.x = siluf_(bb.x + x0.x * w0.x + x1.x * w0.y + x2.x * w0.z + x3.x * w0.w);
    v.y = siluf_(bb.y + x0.y * w1.x + x1.y * w1.y + x2.y * w1.z + x3.y * w1.w);
    v.z = siluf_(bb.z + x0.z * w2.x + x1.z * w2.y + x2.z * w2.z + x3.z * w2.w);
    v.w = siluf_(bb.w + x0.w * w3.x + x1.w * w3.y + x2.w * w3.z + x3.w * w3.w);
    ((float4*)value)[i] = v;
    HS a = split1(v.x), b = split1(v.y), c = split1(v.z), d = split1(v.w);
    u16x4 h, s;
    h.x = a.h; h.y = b.h; h.z = c.h; h.w = d.h;
    s.x = a.s; s.y = b.s; s.z = c.s; s.w = d.s;
    ((u16x4*)vh)[i] = h;
    ((u16x4*)vl)[i] = s;
}

// per (bt,h,n): dt (softplus+clip), S = 1/(1 + dt*kd + dt^2*A)
__global__ __launch_bounds__(256) void dtkd_S_kernel(const float* __restrict__ proj,
                                                     const float* __restrict__ dt_bias,
                                                     const float* __restrict__ A_log,
                                                     float* __restrict__ dt_a,
                                                     float* __restrict__ S_a) {
    int idx = blockIdx.x * 256 + threadIdx.x;     // < BT*NH*NS
    int n = idx & (NS - 1);
    int h = (idx >> 5) & (NH - 1);
    int bt = idx >> 10;
    const float* prow = proj + (size_t)bt * PROJW + 2 * DI;
    float p0 = prow[2 * h], p1 = prow[2 * h + 1];
    float xdt = p0 + dt_bias[h];
    float sp = fmaxf(xdt, 0.0f) + log1pf(expf(-fabsf(xdt)));
    float dt = fminf(fmaxf(sp, 1e-4f), 0.1f);
    float kd = 0.5f * sigmoidf_(p1);
    float A = expf(A_log[h * NS + n]);
    float S = 1.0f / (1.0f + dt * kd + dt * dt * A);
    S_a[idx] = S;
    if (n == 0) dt_a[bt * NH + h] = dt;
}

// L2-normalize bc over groups of 32
__global__ __launch_bounds__(256) void normalize_kernel(float* __restrict__ bc) {
    int idx = blockIdx.x * 256 + threadIdx.x;     // < BT*4096
    float v = bc[idx];
    float ss = v * v;
    ss += __shfl_xor(ss, 1);
    ss += __shfl_xor(ss, 2);
    ss += __shfl_xor(ss, 4);
    ss += __shfl_xor(ss, 8);
    ss += __shfl_xor(ss, 16);
    bc[idx] = v / (sqrtf(ss) + 1e-8f);
}

// ---------------------------------------------------------------------------
// sequential scan, chunked LDS staging (m201-style double buffer):
// per chunk of 64 steps, each wave issues 15 global_load_lds; ONE counted
// vmcnt(15) + raw s_barrier per chunk; 64 steps then read LDS only.
// One block per (b,h); wave w owns d in [16w,16w+16); lane group ng owns
// n in [8ng,8ng+8).
// ---------------------------------------------------------------------------
#define CH 64
#define NCH (TT / CH)

__global__ __launch_bounds__(256, 1) void scan_kernel(const float* __restrict__ value,
                                                      const float* __restrict__ bc,
                                                      const float* __restrict__ dt_a,
                                                      const float* __restrict__ S_a,
                                                      const float* __restrict__ A_log,
                                                      float* __restrict__ yout) {
    __shared__ float bcb[2][CH * 128];   // 64 KB
    __shared__ float Sb [2][CH * 32];    // 16 KB
    __shared__ float ub [2][CH * 64];    // 32 KB
    __shared__ float dtb[2][4 * CH];     //  2 KB (per-wave private dt copies)

    const int bh = blockIdx.x;
    const int b = bh >> 5, h = bh & (NH - 1);
    const int tid = threadIdx.x;
    const int w = tid >> 6, l = tid & 63;
    const int dloc = l & 15;
    const int ng = l >> 4;
    const int n0 = ng * 8;
    const int r0 = w * 16;               // this wave's staging row range

    const float* bc0 = bc    + (size_t)b * TT * 4096 + h * 128;
    const float* S0  = S_a   + (size_t)b * TT * 1024 + h * 32;
    const float* u0  = value + (size_t)b * TT * DI   + h * DH;
    const float* dt0 = dt_a  + (size_t)b * TT * NH   + h;

    float a[8];
#pragma unroll
    for (int j = 0; j < 8; j++) a[j] = expf(A_log[h * NS + n0 + j]);

    float z[8], s[8];
#pragma unroll
    for (int j = 0; j < 8; j++) { z[j] = 0.0f; s[j] = 0.0f; }

    float* yp = yout + (size_t)b * TT * DI + h * DH + w * 16 + dloc;

    auto issue_chunk = [&](int t0, int bi) {
        // bc rows r0..r0+15 (2 rows per 1KB issue -> 8 issues)
        {
            const float* src = bc0 + (size_t)(t0 + r0 + (l >> 5)) * 4096 + (l & 31) * 4;
            float* dst = &bcb[bi][r0 * 128];
#pragma unroll
            for (int i = 0; i < 8; ++i) {
                async_copy16(src, dst);
                src += 2 * 4096; dst += 2 * 128;
            }
        }
        // S rows (8 rows per issue -> 2 issues)
        {
            const float* src = S0 + (size_t)(t0 + r0 + (l >> 3)) * 1024 + (l & 7) * 4;
            float* dst = &Sb[bi][r0 * 32];
#pragma unroll
            for (int i = 0; i < 2; ++i) {
                async_copy16(src, dst);
                src += 8 * 1024; dst += 8 * 32;
            }
        }
        // u rows (4 rows per issue -> 4 issues)
        {
            const float* src = u0 + (size_t)(t0 + r0 + (l >> 4)) * DI + (l & 15) * 4;
            float* dst = &ub[bi][r0 * 64];
#pragma unroll
            for (int i = 0; i < 4; ++i) {
                async_copy16(src, dst);
                src += 4 * DI; dst += 4 * 64;
            }
        }
        // dt: per-wave private copy of all 64 steps (1 issue, 4B/lane)
        {
            const float* src = dt0 + (size_t)(t0 + l) * NH;
            float* dst = &dtb[bi][w * CH];
            async_copy4(src, dst);
        }
    };

    issue_chunk(0, 0);

    for (int c = 0; c < NCH; ++c) {
        const int bi = c & 1;
        if (c + 1 < NCH) {
            issue_chunk((c + 1) * CH, bi ^ 1);
            asm volatile("s_waitcnt vmcnt(15)" ::: "memory");   // chunk c's 15 loads done
        } else {
            asm volatile("s_waitcnt vmcnt(0)" ::: "memory");
        }
        __builtin_amdgcn_sched_barrier(0);
        __builtin_amdgcn_s_barrier();                           // all waves' chunk-c loads visible

#pragma unroll 2
        for (int r = 0; r < CH; ++r) {
            const float* bcr = &bcb[bi][r * 128];
            float bz[8], bx[8], cz[8], cx[8], Sv[8];
            *(float4*)&bz[0] = *(const float4*)&bcr[n0];
            *(float4*)&bz[4] = *(const float4*)&bcr[n0 + 4];
            *(float4*)&bx[0] = *(const float4*)&bcr[32 + n0];
            *(float4*)&bx[4] = *(const float4*)&bcr[32 + n0 + 4];
            *(float4*)&cz[0] = *(const float4*)&bcr[64 + n0];
            *(float4*)&cz[4] = *(const float4*)&bcr[64 + n0 + 4];
            *(float4*)&cx[0] = *(const float4*)&bcr[96 + n0];
            *(float4*)&cx[4] = *(const float4*)&bcr[96 + n0 + 4];
            const float* Sr = &Sb[bi][r * 32 + n0];
            *(float4*)&Sv[0] = *(const float4*)&Sr[0];
            *(float4*)&Sv[4] = *(const float4*)&Sr[4];
            float u_d = ub[bi][r * 64 + w * 16 + dloc];
            float dt = dtb[bi][w * CH + r];

            float dtu = dt * u_d;
            float y0 = 0.0f, y1 = 0.0f;
#pragma unroll
            for (int j = 0; j < 8; j++) {
                float dtA = dt * a[j];
                float t1v = fmaf(-dtA, s[j], z[j]);
                float t2v = fmaf(dtu, bz[j], t1v);
                float zn = Sv[j] * t2v;
                z[j] = zn;
                float sn = fmaf(dt, zn, fmaf(dtu, bx[j], s[j]));
                s[j] = sn;
                if (j & 1) { y1 = fmaf(cz[j], zn, y1); y1 = fmaf(cx[j], sn, y1); }
                else       { y0 = fmaf(cz[j], zn, y0); y0 = fmaf(cx[j], sn, y0); }
            }
            float y = y0 + y1;
            y += __shfl_xor(y, 16);
            y += __shfl_xor(y, 32);
            if (ng == 0) yp[(size_t)(c * CH + r) * DI] = y;
        }
        __builtin_amdgcn_s_barrier();   // all waves done reading buf bi before it is overwritten
    }
}

// y = (y + skip*value) * silu(gate); writes bf16 split only (consumed by GEMM3)
__global__ __launch_bounds__(256) void fuse_kernel(const float* __restrict__ proj,
                                                   const float* __restrict__ value,
                                                   const float* __restrict__ skip,
                                                   const float* __restrict__ ysc,
                                                   u16* __restrict__ yh,
                                                   u16* __restrict__ yl) {
    int i = blockIdx.x * 256 + threadIdx.x;      // < BT*DI/4
    int dq = i & (DI / 4 - 1);
    int bt = i >> 9;
    int di = dq * 4;
    float4 g = *(const float4*)&proj[(size_t)bt * PROJW + di];
    float4 yv = ((const float4*)ysc)[i];
    float4 v = ((const float4*)value)[i];
    float4 sk = *(const float4*)&skip[di];
    float4 r;
    r.x = fmaf(sk.x, v.x, yv.x) * siluf_(g.x);
    r.y = fmaf(sk.y, v.y, yv.y) * siluf_(g.y);
    r.z = fmaf(sk.z, v.z, yv.z) * siluf_(g.z);
    r.w = fmaf(sk.w, v.w, yv.w) * siluf_(g.w);
    HS a = split1(r.x), b = split1(r.y), c = split1(r.z), d = split1(r.w);
    u16x4 h, s;
    h.x = a.h; h.y = b.h; h.z = c.h; h.w = d.h;
    s.x = a.s; s.y = b.s; s.z = c.s; s.w = d.s;
    ((u16x4*)yh)[i] = h;
    ((u16x4*)yl)[i] = s;
}

extern "C" void kernel_launch(void* const* d_in, const int* in_sizes, int n_in,
                              void* d_out, int out_size, void* d_ws, size_t ws_size,
                              hipStream_t stream) {
    const float* x       = (const float*)d_in[0];
    const float* W_in    = (const float*)d_in[1];
    const float* dw_w    = (const float*)d_in[2];
    const float* dw_b    = (const float*)d_in[3];
    const float* W_bc    = (const float*)d_in[4];
    const float* W_out   = (const float*)d_in[5];
    const float* skip    = (const float*)d_in[6];
    const float* A_log   = (const float*)d_in[7];
    const float* dt_bias = (const float*)d_in[8];
    float* out = (float*)d_out;

    float* ws    = (float*)d_ws;
    float* proj  = ws;                                // 4,259,840 f
    float* value = proj  + (size_t)BT * PROJW;        // 2,097,152
    float* dt_a  = value + (size_t)BT * DI;           // 32,768
    float* S_a   = dt_a  + (size_t)BT * NH;           // 1,048,576
    float* bcw   = S_a   + (size_t)BT * NH * NS;      // 4,194,304
    float* ysc   = bcw   + (size_t)BT * 4096;         // 2,097,152
    u16* Aslot_h = (u16*)(ysc + (size_t)BT * DI);     // 2,097,152 u16
    u16* Aslot_l = Aslot_h + 2097152;                 // 2,097,152
    u16* Bslot_h = Aslot_l + 2097152;                 // 8,388,608
    u16* Bslot_l = Bslot_h + 8388608;                 // 8,388,608

    dim3 blk(256);

    // splits for GEMM1: A = x (1,048,576), B = W_in (4,259,840)
    split_kernel<<<dim3(1048576 / 4 / 256), blk, 0, stream>>>(x, Aslot_h, Aslot_l, 1048576 / 4);
    split_kernel<<<dim3(4259840 / 4 / 256), blk, 0, stream>>>(W_in, Bslot_h, Bslot_l, 4259840 / 4);

    // 1) proj = x @ W_in^T : M=1024, N=4160, K=1024 (N edge guarded)
    gemm_bf16x3<64, 128, true><<<dim3(33, 16), blk, 0, stream>>>(
        Aslot_h, Aslot_l, Bslot_h, Bslot_l, proj, BT, PROJW, DM);

    // 2) conv + silu -> value (fp32 + bf16 split into A slot)
    conv_silu_kernel<<<dim3(BT * DI / 4 / 256), blk, 0, stream>>>(
        proj, dw_w, dw_b, value, Aslot_h, Aslot_l);

    // 3) dt + S precompute
    dtkd_S_kernel<<<dim3(BT * NH * NS / 256), blk, 0, stream>>>(proj, dt_bias, A_log, dt_a, S_a);

    // split B = W_bc (8,388,608)
    split_kernel<<<dim3(8388608 / 4 / 256), blk, 0, stream>>>(W_bc, Bslot_h, Bslot_l, 8388608 / 4);

    // 4) bc = value @ W_bc^T : M=1024, N=4096, K=2048
    gemm_bf16x3<64, 128, false><<<dim3(32, 16), blk, 0, stream>>>(
        Aslot_h, Aslot_l, Bslot_h, Bslot_l, bcw, BT, 4096, DI);

    // 5) normalize
    normalize_kernel<<<dim3(BT * 4096 / 256), blk, 0, stream>>>(bcw);

    // 6) scan (chunked LDS double-buffer)
    scan_kernel<<<dim3(BB * NH), blk, 0, stream>>>(value, bcw, dt_a, S_a, A_log, ysc);

    // 7) fuse skip/gate -> bf16 split into A slot
    fuse_kernel<<<dim3(BT * DI / 4 / 256), blk, 0, stream>>>(
        proj, value, skip, ysc, Aslot_h, Aslot_l);

    // split B = W_out (2,097,152)
    split_kernel<<<dim3(2097152 / 4 / 256), blk, 0, stream>>>(W_out, Bslot_h, Bslot_l, 2097152 / 4);

    // 8) out = y @ W_out^T : M=1024, N=1024, K=2048
    gemm_bf16x3<64, 64, false><<<dim3(16, 16), blk, 0, stream>>>(
        Aslot_h, Aslot_l, Bslot_h, Bslot_l, out, BT, DM, DI);
}

// Round 10
// 406.820 us; speedup vs baseline: 1.5325x; 1.1237x over previous
//
#include <hip/hip_runtime.h>
#include <hip/hip_bf16.h>
#include <math.h>

// Problem constants
#define BB 2
#define TT 512
#define DM 1024
#define DI 2048
#define DCONV 4
#define NH 32
#define NS 32
#define DH 64
#define PROJW 4160   // 2*DI + NH*2
#define BT (BB*TT)   // 1024

typedef unsigned short u16;
typedef short bf16x8v __attribute__((ext_vector_type(8)));
typedef float f32x4 __attribute__((ext_vector_type(4)));
typedef u16 u16x4 __attribute__((ext_vector_type(4)));

__device__ __forceinline__ float sigmoidf_(float x) { return 1.0f / (1.0f + expf(-x)); }
__device__ __forceinline__ float siluf_(float x) { return x * sigmoidf_(x); }

// RNE split: x ~= h + s (both bf16), returned by value
struct HS { u16 h, s; };
__device__ __forceinline__ HS split1(float x) {
    HS r;
    unsigned u = __float_as_uint(x);
    unsigned rr = u + 0x7fffu + ((u >> 16) & 1u);
    r.h = (u16)(rr >> 16);
    float hf = __uint_as_float(((unsigned)r.h) << 16);
    float res = x - hf;
    unsigned u2 = __float_as_uint(res);
    unsigned r2 = u2 + 0x7fffu + ((u2 >> 16) & 1u);
    r.s = (u16)(r2 >> 16);
    return r;
}

__device__ __forceinline__ void async_copy16(const void* g, void* l) {
    __builtin_amdgcn_global_load_lds(
        (__attribute__((address_space(1))) void*)const_cast<void*>(g),
        (__attribute__((address_space(3))) void*)l,
        16, 0, 0);
}

__device__ __forceinline__ void async_copy4(const void* g, void* l) {
    __builtin_amdgcn_global_load_lds(
        (__attribute__((address_space(1))) void*)const_cast<void*>(g),
        (__attribute__((address_space(3))) void*)l,
        4, 0, 0);
}

// elementwise fp32 -> (hi, lo) bf16 arrays, 4 elems/thread
__global__ __launch_bounds__(256) void split_kernel(const float* __restrict__ in,
                                                    u16* __restrict__ hi,
                                                    u16* __restrict__ lo,
                                                    int n4) {
    int i = blockIdx.x * 256 + threadIdx.x;
    if (i >= n4) return;
    float4 v = ((const float4*)in)[i];
    HS a = split1(v.x), b = split1(v.y), c = split1(v.z), d = split1(v.w);
    u16x4 h, s;
    h.x = a.h; h.y = b.h; h.z = c.h; h.w = d.h;
    s.x = a.s; s.y = b.s; s.z = c.s; s.w = d.s;
    ((u16x4*)hi)[i] = h;
    ((u16x4*)lo)[i] = s;
}

// ---------------------------------------------------------------------------
// bf16x3 MFMA NT-GEMM: C[m,n] = sum_k A[m,k]*B[n,k], A=Ah+Al, B=Bh+Bl.
// ---------------------------------------------------------------------------
template<int BM, int BN, bool GUARD>
__global__ __launch_bounds__(256) void gemm_bf16x3(const u16* __restrict__ Ah,
                                                   const u16* __restrict__ Al,
                                                   const u16* __restrict__ Bh,
                                                   const u16* __restrict__ Bl,
                                                   float* __restrict__ C,
                                                   int M, int N, int K) {
    constexpr int MF = BM / 32;
    constexpr int NF = BN / 32;
    constexpr int ASEG = BM / 16, BSEG = BN / 16;
    constexpr int NSEG = 2 * ASEG + 2 * BSEG;
    constexpr int SEGW = NSEG / 4;

    __shared__ u16 lds[(2 * BM + 2 * BN) * 32];
    u16* Ah_s = lds;
    u16* Al_s = lds + BM * 32;
    u16* Bh_s = lds + 2 * BM * 32;
    u16* Bl_s = lds + (2 * BM + BN) * 32;

    const int tid = threadIdx.x;
    const int l = tid & 63;
    const int w = tid >> 6;
    const int wm = w >> 1, wn = w & 1;

    const int m0 = blockIdx.y * BM;
    const int n0 = blockIdx.x * BN;

    const u16* segg[SEGW];
    u16* segl[SEGW];
#pragma unroll
    for (int si = 0; si < SEGW; ++si) {
        int seg = w + si * 4;
        const u16* gmat;
        u16* lmat;
        int r0, rbase;
        if (seg < ASEG)                { gmat = Ah; lmat = Ah_s; r0 = seg * 16;                  rbase = m0; }
        else if (seg < 2 * ASEG)       { gmat = Al; lmat = Al_s; r0 = (seg - ASEG) * 16;         rbase = m0; }
        else if (seg < 2 * ASEG + BSEG){ gmat = Bh; lmat = Bh_s; r0 = (seg - 2 * ASEG) * 16;     rbase = n0; }
        else                           { gmat = Bl; lmat = Bl_s; r0 = (seg - 2 * ASEG - BSEG) * 16; rbase = n0; }
        segg[si] = gmat + (size_t)(rbase + r0 + (l >> 2)) * K + (l & 3) * 8;
        segl[si] = lmat + r0 * 32;
    }

    f32x4 acc[MF][NF];
#pragma unroll
    for (int i = 0; i < MF; ++i)
#pragma unroll
        for (int j = 0; j < NF; ++j) {
            f32x4 z = {0.0f, 0.0f, 0.0f, 0.0f};
            acc[i][j] = z;
        }

    const int lrow = l & 15;
    const int lko = (l >> 4) * 8;

    for (int k0 = 0; k0 < K; k0 += 32) {
#pragma unroll
        for (int si = 0; si < SEGW; ++si)
            async_copy16(segg[si] + k0, segl[si]);
        __syncthreads();

        bf16x8v af[MF][2], bfv[NF][2];
#pragma unroll
        for (int i = 0; i < MF; ++i) {
            int r = wm * (MF * 16) + i * 16 + lrow;
            af[i][0] = *(const bf16x8v*)&Ah_s[r * 32 + lko];
            af[i][1] = *(const bf16x8v*)&Al_s[r * 32 + lko];
        }
#pragma unroll
        for (int j = 0; j < NF; ++j) {
            int r = wn * (NF * 16) + j * 16 + lrow;
            bfv[j][0] = *(const bf16x8v*)&Bh_s[r * 32 + lko];
            bfv[j][1] = *(const bf16x8v*)&Bl_s[r * 32 + lko];
        }
#pragma unroll
        for (int i = 0; i < MF; ++i)
#pragma unroll
            for (int j = 0; j < NF; ++j) {
                acc[i][j] = __builtin_amdgcn_mfma_f32_16x16x32_bf16(af[i][0], bfv[j][0], acc[i][j], 0, 0, 0);
                acc[i][j] = __builtin_amdgcn_mfma_f32_16x16x32_bf16(af[i][0], bfv[j][1], acc[i][j], 0, 0, 0);
                acc[i][j] = __builtin_amdgcn_mfma_f32_16x16x32_bf16(af[i][1], bfv[j][0], acc[i][j], 0, 0, 0);
            }
        __syncthreads();
    }

#pragma unroll
    for (int i = 0; i < MF; ++i) {
        int mrow = m0 + wm * (MF * 16) + i * 16 + (l >> 4) * 4;
#pragma unroll
        for (int j = 0; j < NF; ++j) {
            int ncol = n0 + wn * (NF * 16) + j * 16 + lrow;
            if (!GUARD || ncol < N) {
#pragma unroll
                for (int r = 0; r < 4; ++r)
                    C[(size_t)(mrow + r) * N + ncol] = acc[i][j][r];
            }
        }
    }
}

// depthwise causal conv (K=4) + SiLU, 4 channels/thread; also writes bf16 split
__global__ __launch_bounds__(256) void conv_silu_kernel(const float* __restrict__ proj,
                                                        const float* __restrict__ dw_w,
                                                        const float* __restrict__ dw_b,
                                                        float* __restrict__ value,
                                                        u16* __restrict__ vh,
                                                        u16* __restrict__ vl) {
    int i = blockIdx.x * 256 + threadIdx.x;      // < BT*DI/4
    int dq = i & (DI / 4 - 1);
    int bt = i >> 9;
    int t = bt & (TT - 1);
    int di = dq * 4;
    const float* vr = proj + (size_t)bt * PROJW + DI + di;
    float4 zz = {0, 0, 0, 0};
    float4 x0 = (t >= 3) ? *(const float4*)(vr - 3 * PROJW) : zz;
    float4 x1 = (t >= 2) ? *(const float4*)(vr - 2 * PROJW) : zz;
    float4 x2 = (t >= 1) ? *(const float4*)(vr - 1 * PROJW) : zz;
    float4 x3 = *(const float4*)vr;
    float4 w0 = *(const float4*)&dw_w[(di + 0) * 4];
    float4 w1 = *(const float4*)&dw_w[(di + 1) * 4];
    float4 w2 = *(const float4*)&dw_w[(di + 2) * 4];
    float4 w3 = *(const float4*)&dw_w[(di + 3) * 4];
    float4 bb = *(const float4*)&dw_b[di];
    float4 v;
    v.x = siluf_(bb.x + x0.x * w0.x + x1.x * w0.y + x2.x * w0.z + x3.x * w0.w);
    v.y = siluf_(bb.y + x0.y * w1.x + x1.y * w1.y + x2.y * w1.z + x3.y * w1.w);
    v.z = siluf_(bb.z + x0.z * w2.x + x1.z * w2.y + x2.z * w2.z + x3.z * w2.w);
    v.w = siluf_(bb.w + x0.w * w3.x + x1.w * w3.y + x2.w * w3.z + x3.w * w3.w);
    ((float4*)value)[i] = v;
    HS a = split1(v.x), b = split1(v.y), c = split1(v.z), d = split1(v.w);
    u16x4 h, s;
    h.x = a.h; h.y = b.h; h.z = c.h; h.w = d.h;
    s.x = a.s; s.y = b.s; s.z = c.s; s.w = d.s;
    ((u16x4*)vh)[i] = h;
    ((u16x4*)vl)[i] = s;
}

// per (bt,h,n): dt (softplus+clip), S = 1/(1 + dt*kd + dt^2*A)
__global__ __launch_bounds__(256) void dtkd_S_kernel(const float* __restrict__ proj,
                                                     const float* __restrict__ dt_bias,
                                                     const float* __restrict__ A_log,
                                                     float* __restrict__ dt_a,
                                                     float* __restrict__ S_a) {
    int idx = blockIdx.x * 256 + threadIdx.x;     // < BT*NH*NS
    int n = idx & (NS - 1);
    int h = (idx >> 5) & (NH - 1);
    int bt = idx >> 10;
    const float* prow = proj + (size_t)bt * PROJW + 2 * DI;
    float p0 = prow[2 * h], p1 = prow[2 * h + 1];
    float xdt = p0 + dt_bias[h];
    float sp = fmaxf(xdt, 0.0f) + log1pf(expf(-fabsf(xdt)));
    float dt = fminf(fmaxf(sp, 1e-4f), 0.1f);
    float kd = 0.5f * sigmoidf_(p1);
    float A = expf(A_log[h * NS + n]);
    float S = 1.0f / (1.0f + dt * kd + dt * dt * A);
    S_a[idx] = S;
    if (n == 0) dt_a[bt * NH + h] = dt;
}

// L2-normalize bc over groups of 32
__global__ __launch_bounds__(256) void normalize_kernel(float* __restrict__ bc) {
    int idx = blockIdx.x * 256 + threadIdx.x;     // < BT*4096
    float v = bc[idx];
    float ss = v * v;
    ss += __shfl_xor(ss, 1);
    ss += __shfl_xor(ss, 2);
    ss += __shfl_xor(ss, 4);
    ss += __shfl_xor(ss, 8);
    ss += __shfl_xor(ss, 16);
    bc[idx] = v / (sqrtf(ss) + 1e-8f);
}

// ---------------------------------------------------------------------------
// sequential scan, v4: 4-way d-split (256 blocks, XCD-colocated per (b,h)),
// chunked LDS double-buffer, explicit 4-buffer register pipeline (LDS reads
// issued ~2 steps ahead of use). One vmcnt(0)+s_barrier per 64-step chunk.
// Block (part,bh): handles d in [part*16, part*16+16). 256 thr = 4 waves.
// Wave w: d_local = w*4 + (l>>4); lane group g = l&15 owns n in {2g, 2g+1}.
// ---------------------------------------------------------------------------
#define CH 64
#define NCH (TT / CH)

struct SReg2 { float bz[2], bx[2], cz[2], cx[2], S[2], u, dt; };

__global__ __launch_bounds__(256, 1) void scan_kernel(const float* __restrict__ value,
                                                      const float* __restrict__ bc,
                                                      const float* __restrict__ dt_a,
                                                      const float* __restrict__ S_a,
                                                      const float* __restrict__ A_log,
                                                      float* __restrict__ yout) {
    __shared__ float bcb[2][CH * 128];   // 64 KB
    __shared__ float Sb [2][CH * 32];    // 16 KB
    __shared__ float ub [2][CH * 16];    //  8 KB
    __shared__ float dtb[2][4 * CH];     //  2 KB

    const int part = blockIdx.x >> 6;          // 0..3 (d-split)
    const int bh = blockIdx.x & 63;            // same bh -> same XCD (idx mod 8)
    const int b = bh >> 5, h = bh & (NH - 1);
    const int tid = threadIdx.x;
    const int w = tid >> 6, l = tid & 63;
    const int g = l & 15;
    const int dl = w * 4 + (l >> 4);           // d_local 0..15
    const int d0 = part * 16;
    const int n0 = 2 * g;
    const int r0 = w * 16;                     // this wave's staging rows

    const float* bc0 = bc    + (size_t)b * TT * 4096 + h * 128;
    const float* S0  = S_a   + (size_t)b * TT * 1024 + h * 32;
    const float* u0  = value + (size_t)b * TT * DI   + h * DH + d0;
    const float* dt0 = dt_a  + (size_t)b * TT * NH   + h;

    float a[2];
    a[0] = expf(A_log[h * NS + n0]);
    a[1] = expf(A_log[h * NS + n0 + 1]);

    float z[2] = {0.0f, 0.0f}, s[2] = {0.0f, 0.0f};

    float* yp = yout + (size_t)b * TT * DI + h * DH + d0 + dl;

    int bi = 0;

    auto issue_chunk = [&](int t0, int dbuf) {
        {   // bc: 16 rows x 512B -> 8 issues
            const float* src = bc0 + (size_t)(t0 + r0 + (l >> 5)) * 4096 + (l & 31) * 4;
            float* dst = &bcb[dbuf][r0 * 128];
#pragma unroll
            for (int i = 0; i < 8; ++i) {
                async_copy16(src, dst);
                src += 2 * 4096; dst += 2 * 128;
            }
        }
        {   // S: 16 rows x 128B -> 2 issues
            const float* src = S0 + (size_t)(t0 + r0 + (l >> 3)) * 1024 + (l & 7) * 4;
            float* dst = &Sb[dbuf][r0 * 32];
#pragma unroll
            for (int i = 0; i < 2; ++i) {
                async_copy16(src, dst);
                src += 8 * 1024; dst += 8 * 32;
            }
        }
        {   // u: 16 rows x 64B -> 1 issue
            const float* src = u0 + (size_t)(t0 + r0 + (l >> 2)) * DI + (l & 3) * 4;
            async_copy16(src, &ub[dbuf][r0 * 16]);
        }
        {   // dt: 64 steps, per-wave copy -> 1 issue
            const float* src = dt0 + (size_t)(t0 + l) * NH;
            async_copy4(src, &dtb[dbuf][w * CH]);
        }
    };

    auto ldr = [&](SReg2& rg, int r) {
        const float* bcr = &bcb[bi][r * 128];
        *(float2*)&rg.bz[0] = *(const float2*)&bcr[n0];
        *(float2*)&rg.bx[0] = *(const float2*)&bcr[32 + n0];
        *(float2*)&rg.cz[0] = *(const float2*)&bcr[64 + n0];
        *(float2*)&rg.cx[0] = *(const float2*)&bcr[96 + n0];
        *(float2*)&rg.S[0]  = *(const float2*)&Sb[bi][r * 32 + n0];
        rg.u  = ub[bi][r * 16 + dl];
        rg.dt = dtb[bi][w * CH + r];
    };

    auto stepc = [&](SReg2& rg) {
        float dt = rg.dt;
        float dtu = dt * rg.u;
        float y = 0.0f;
#pragma unroll
        for (int j = 0; j < 2; ++j) {
            float dtA = dt * a[j];
            float t1v = fmaf(-dtA, s[j], z[j]);
            float t2v = fmaf(dtu, rg.bz[j], t1v);
            float zn = rg.S[j] * t2v;
            z[j] = zn;
            float sn = fmaf(dt, zn, fmaf(dtu, rg.bx[j], s[j]));
            s[j] = sn;
            y = fmaf(rg.cz[j], zn, y);
            y = fmaf(rg.cx[j], sn, y);
        }
        y += __shfl_xor(y, 1);
        y += __shfl_xor(y, 2);
        y += __shfl_xor(y, 4);
        y += __shfl_xor(y, 8);
        if (g == 0) *yp = y;
        yp += DI;
    };

    issue_chunk(0, 0);

    for (int c = 0; c < NCH; ++c) {
        bi = c & 1;
        // my chunk-c loads (issued one chunk ago) + my old stores: all retired
        // or nearly so -> cheap drain; barrier makes every wave's data visible.
        asm volatile("s_waitcnt vmcnt(0)" ::: "memory");
        __builtin_amdgcn_s_barrier();
        if (c + 1 < NCH) issue_chunk((c + 1) * CH, bi ^ 1);

        SReg2 q0, q1, q2, q3;
        ldr(q0, 0); ldr(q1, 1);
        for (int p = 0; p < CH / 4; ++p) {
            ldr(q2, 4 * p + 2);              stepc(q0);
            ldr(q3, 4 * p + 3);              stepc(q1);
            ldr(q0, (4 * p + 4) & (CH - 1)); stepc(q2);
            ldr(q1, (4 * p + 5) & (CH - 1)); stepc(q3);
        }
    }
}

// y = (y + skip*value) * silu(gate); writes bf16 split only (consumed by GEMM3)
__global__ __launch_bounds__(256) void fuse_kernel(const float* __restrict__ proj,
                                                   const float* __restrict__ value,
                                                   const float* __restrict__ skip,
                                                   const float* __restrict__ ysc,
                                                   u16* __restrict__ yh,
                                                   u16* __restrict__ yl) {
    int i = blockIdx.x * 256 + threadIdx.x;      // < BT*DI/4
    int dq = i & (DI / 4 - 1);
    int bt = i >> 9;
    int di = dq * 4;
    float4 g = *(const float4*)&proj[(size_t)bt * PROJW + di];
    float4 yv = ((const float4*)ysc)[i];
    float4 v = ((const float4*)value)[i];
    float4 sk = *(const float4*)&skip[di];
    float4 r;
    r.x = fmaf(sk.x, v.x, yv.x) * siluf_(g.x);
    r.y = fmaf(sk.y, v.y, yv.y) * siluf_(g.y);
    r.z = fmaf(sk.z, v.z, yv.z) * siluf_(g.z);
    r.w = fmaf(sk.w, v.w, yv.w) * siluf_(g.w);
    HS a = split1(r.x), b = split1(r.y), c = split1(r.z), d = split1(r.w);
    u16x4 h, s;
    h.x = a.h; h.y = b.h; h.z = c.h; h.w = d.h;
    s.x = a.s; s.y = b.s; s.z = c.s; s.w = d.s;
    ((u16x4*)yh)[i] = h;
    ((u16x4*)yl)[i] = s;
}

extern "C" void kernel_launch(void* const* d_in, const int* in_sizes, int n_in,
                              void* d_out, int out_size, void* d_ws, size_t ws_size,
                              hipStream_t stream) {
    const float* x       = (const float*)d_in[0];
    const float* W_in    = (const float*)d_in[1];
    const float* dw_w    = (const float*)d_in[2];
    const float* dw_b    = (const float*)d_in[3];
    const float* W_bc    = (const float*)d_in[4];
    const float* W_out   = (const float*)d_in[5];
    const float* skip    = (const float*)d_in[6];
    const float* A_log   = (const float*)d_in[7];
    const float* dt_bias = (const float*)d_in[8];
    float* out = (float*)d_out;

    float* ws    = (float*)d_ws;
    float* proj  = ws;                                // 4,259,840 f
    float* value = proj  + (size_t)BT * PROJW;        // 2,097,152
    float* dt_a  = value + (size_t)BT * DI;           // 32,768
    float* S_a   = dt_a  + (size_t)BT * NH;           // 1,048,576
    float* bcw   = S_a   + (size_t)BT * NH * NS;      // 4,194,304
    float* ysc   = bcw   + (size_t)BT * 4096;         // 2,097,152
    u16* Aslot_h = (u16*)(ysc + (size_t)BT * DI);     // 2,097,152 u16
    u16* Aslot_l = Aslot_h + 2097152;                 // 2,097,152
    u16* Bslot_h = Aslot_l + 2097152;                 // 8,388,608
    u16* Bslot_l = Bslot_h + 8388608;                 // 8,388,608

    dim3 blk(256);

    // splits for GEMM1: A = x (1,048,576), B = W_in (4,259,840)
    split_kernel<<<dim3(1048576 / 4 / 256), blk, 0, stream>>>(x, Aslot_h, Aslot_l, 1048576 / 4);
    split_kernel<<<dim3(4259840 / 4 / 256), blk, 0, stream>>>(W_in, Bslot_h, Bslot_l, 4259840 / 4);

    // 1) proj = x @ W_in^T : M=1024, N=4160, K=1024 (N edge guarded)
    gemm_bf16x3<64, 128, true><<<dim3(33, 16), blk, 0, stream>>>(
        Aslot_h, Aslot_l, Bslot_h, Bslot_l, proj, BT, PROJW, DM);

    // 2) conv + silu -> value (fp32 + bf16 split into A slot)
    conv_silu_kernel<<<dim3(BT * DI / 4 / 256), blk, 0, stream>>>(
        proj, dw_w, dw_b, value, Aslot_h, Aslot_l);

    // 3) dt + S precompute
    dtkd_S_kernel<<<dim3(BT * NH * NS / 256), blk, 0, stream>>>(proj, dt_bias, A_log, dt_a, S_a);

    // split B = W_bc (8,388,608)
    split_kernel<<<dim3(8388608 / 4 / 256), blk, 0, stream>>>(W_bc, Bslot_h, Bslot_l, 8388608 / 4);

    // 4) bc = value @ W_bc^T : M=1024, N=4096, K=2048
    gemm_bf16x3<64, 128, false><<<dim3(32, 16), blk, 0, stream>>>(
        Aslot_h, Aslot_l, Bslot_h, Bslot_l, bcw, BT, 4096, DI);

    // 5) normalize
    normalize_kernel<<<dim3(BT * 4096 / 256), blk, 0, stream>>>(bcw);

    // 6) scan (4-way d-split + chunked LDS dbuf + register pipeline)
    scan_kernel<<<dim3(4 * BB * NH), blk, 0, stream>>>(value, bcw, dt_a, S_a, A_log, ysc);

    // 7) fuse skip/gate -> bf16 split into A slot
    fuse_kernel<<<dim3(BT * DI / 4 / 256), blk, 0, stream>>>(
        proj, value, skip, ysc, Aslot_h, Aslot_l);

    // split B = W_out (2,097,152)
    split_kernel<<<dim3(2097152 / 4 / 256), blk, 0, stream>>>(W_out, Bslot_h, Bslot_l, 2097152 / 4);

    // 8) out = y @ W_out^T : M=1024, N=1024, K=2048
    gemm_bf16x3<64, 64, false><<<dim3(16, 16), blk, 0, stream>>>(
        Aslot_h, Aslot_l, Bslot_h, Bslot_l, out, BT, DM, DI);
}